// Round 1
// baseline (18136.143 us; speedup 1.0000x reference)
//
#include <hip/hip_runtime.h>
#include <hip/hip_cooperative_groups.h>
#include <math.h>

namespace cg = cooperative_groups;

#define N_    256
#define B_    64
#define S_    256
#define A_    32
#define NSZ   4          // n-columns per block
#define BSZ   16         // batches per block
#define AROWS 33         // 32 action rows + 1 fused static row (J1*cos + Wo + J0)
#define ATS   20         // at_lds row stride (floats); 80B -> float4-aligned rows
#define J0_   (-0.1f)
#define J1_   (0.1f)
#define ALPHA_ 0.15f
#define WIDTH_ 25.6f     // N / 10
#define TWO_PI 6.283185307179586f

#define WA_LDS_FLOATS (NSZ * AROWS * N_)   // 33792
#define AT_LDS_FLOATS (AROWS * ATS)        // 660
#define LDS_BYTES ((WA_LDS_FLOATS + AT_LDS_FLOATS) * 4)  // 137808 B

// Grid: 256 blocks x 256 threads, cooperative. bgroup = bid & 3 (16 batches),
// ngroup = bid >> 2 (4 output columns). One block per CU (LDS-bound), wave w
// owns output column n0+w, lane mq owns m-range [mq*4, mq*4+4).
__global__ __launch_bounds__(256, 1)
void ring_scan_kernel(const float* __restrict__ action,  // [64][256][32]
                      const float* __restrict__ Wo,      // [256][256]
                      const float* __restrict__ Wa,      // [32][256][256]
                      float* __restrict__ out,           // r_hist | bump_hist
                      float* __restrict__ rws)           // ws: 2 * 64*256 floats
{
  cg::grid_group grid = cg::this_grid();
  extern __shared__ float lds[];
  float* wa_lds = lds;                  // [NSZ*AROWS][256], row rl = nl*AROWS + a
  float* at_lds = lds + WA_LDS_FLOATS;  // [AROWS][ATS], transposed a_t
  __shared__ float red[256];

  const int tid = threadIdx.x;
  const int bid = blockIdx.x;
  const int b0  = (bid & 3) * BSZ;
  const int n0  = (bid >> 2) * NSZ;

  // ---- Stage Wa slice + fused static row into LDS (one-time) ----
  for (int c = tid; c < NSZ * AROWS * (N_ / 4); c += 256) {
    const int rl = c >> 6;         // lds row
    const int mq = c & 63;         // float4 index within row
    const int nl = rl / AROWS;
    const int a  = rl - nl * AROWS;
    const int n  = n0 + nl;
    float4 v;
    if (a < A_) {
      v = *reinterpret_cast<const float4*>(Wa + ((size_t)a * N_ + n) * N_ + mq * 4);
    } else {
      const float4 wo = *reinterpret_cast<const float4*>(Wo + (size_t)n * N_ + mq * 4);
      const float* wof = reinterpret_cast<const float*>(&wo);
      float tmp[4];
#pragma unroll
      for (int j = 0; j < 4; ++j) {
        const int m = mq * 4 + j;
        tmp[j] = J0_ + J1_ * cosf((float)(n - m) * (TWO_PI / N_)) + wof[j];
      }
      v = make_float4(tmp[0], tmp[1], tmp[2], tmp[3]);
    }
    *reinterpret_cast<float4*>(wa_lds + rl * N_ + mq * 4) = v;
  }

  // ---- r0 (identical for all batches): bump at center 128, normalized ----
  {
    float dm = fabsf((float)tid - 128.0f);
    dm = fminf(dm, 256.0f - dm);
    const float bv = expf(-dm * dm / (2.0f * WIDTH_ * WIDTH_));
    red[tid] = bv * bv;
    __syncthreads();
    for (int s = 128; s > 0; s >>= 1) {
      if (tid < s) red[tid] += red[tid + s];
      __syncthreads();
    }
    const float inv_norm = 1.0f / sqrtf(red[0]);
    if (tid < BSZ * NSZ) {               // write this block's (b, n) portion
      const int b = b0 + (tid >> 2);
      const int n = n0 + (tid & 3);
      float dn = fabsf((float)n - 128.0f);
      dn = fminf(dn, 256.0f - dn);
      rws[b * N_ + n] = expf(-dn * dn / (2.0f * WIDTH_ * WIDTH_)) * inv_norm;
    }
  }
  __threadfence();
  grid.sync();

  // ---- main scan ----
  const int wv = tid >> 6;     // wave id = local n
  const int mq = tid & 63;     // lane = m chunk (4 floats)
  const int nG = n0 + wv;
  float* rb0 = rws;
  float* rb1 = rws + B_ * N_;
  const float* wrow = wa_lds + wv * AROWS * N_;
  const size_t bump_base = (size_t)B_ * S_ * N_;

  for (int t = 0; t < S_; ++t) {
    const float* rc = (t & 1) ? rb1 : rb0;
    float*       rn = (t & 1) ? rb0 : rb1;

    // issue r loads early (overlap with at staging latency)
    float rr[BSZ][4];
#pragma unroll
    for (int b = 0; b < BSZ; ++b) {
      const float4 v = *reinterpret_cast<const float4*>(rc + (b0 + b) * N_ + mq * 4);
      rr[b][0] = v.x; rr[b][1] = v.y; rr[b][2] = v.z; rr[b][3] = v.w;
    }

    // stage a_t transposed: at_lds[a*ATS + b]; virtual row a=32 -> 1.0
    for (int i = tid; i < BSZ * A_; i += 256) {
      const int b = i >> 5;
      const int a = i & 31;
      at_lds[a * ATS + b] = action[((size_t)(b0 + b) * S_ + t) * A_ + a];
    }
    if (tid < BSZ) at_lds[A_ * ATS + tid] = 1.0f;
    __syncthreads();

    float acc[BSZ];
#pragma unroll
    for (int b = 0; b < BSZ; ++b) acc[b] = 0.0f;

    for (int a = 0; a < AROWS; ++a) {
      const float4 w = *reinterpret_cast<const float4*>(wrow + a * N_ + mq * 4);
      const float* atp = at_lds + a * ATS;
      const float4 t0 = *reinterpret_cast<const float4*>(atp);
      const float4 t1 = *reinterpret_cast<const float4*>(atp + 4);
      const float4 t2 = *reinterpret_cast<const float4*>(atp + 8);
      const float4 t3 = *reinterpret_cast<const float4*>(atp + 12);
      float atv[BSZ];
      atv[0]=t0.x;  atv[1]=t0.y;  atv[2]=t0.z;  atv[3]=t0.w;
      atv[4]=t1.x;  atv[5]=t1.y;  atv[6]=t1.z;  atv[7]=t1.w;
      atv[8]=t2.x;  atv[9]=t2.y;  atv[10]=t2.z; atv[11]=t2.w;
      atv[12]=t3.x; atv[13]=t3.y; atv[14]=t3.z; atv[15]=t3.w;
#pragma unroll
      for (int b = 0; b < BSZ; ++b) {
        const float dd = w.x * rr[b][0] + w.y * rr[b][1] +
                         w.z * rr[b][2] + w.w * rr[b][3];
        acc[b] += atv[b] * dd;
      }
    }

    // butterfly: every lane ends with the full 64-lane sum for all 16 b
#pragma unroll
    for (int off = 1; off < 64; off <<= 1) {
#pragma unroll
      for (int b = 0; b < BSZ; ++b) acc[b] += __shfl_xor(acc[b], off, 64);
    }

    if (mq < BSZ) {
      // static-index select of acc[mq] (no dynamic register indexing)
      float v = acc[0];
#pragma unroll
      for (int b = 1; b < BSZ; ++b) if (mq == b) v = acc[b];
      const int bG = b0 + mq;
      const float rcur = rc[bG * N_ + nG];
      const float rnew = (1.0f - ALPHA_) * rcur + ALPHA_ * fmaxf(v, 0.0f);
      rn[bG * N_ + nG] = rnew;
      out[bump_base + ((size_t)bG * S_ + t) * N_ + nG] = rnew;
    }
    __threadfence();
    grid.sync();
  }

  // ---- epilogue: r_hist = (bump @ Wd) / rowmax, Wd = c c^T + s s^T (rank 2) ----
  float cm[4], sm[4];
#pragma unroll
  for (int j = 0; j < 4; ++j) {
    const float ang = (float)(mq * 4 + j) * (TWO_PI / N_);
    cm[j] = cosf(ang);
    sm[j] = sinf(ang);
  }
  const float* bump = out + bump_base;
  for (int it = 0; it < 16; ++it) {
    const int row = bid * 64 + it * 4 + wv;        // row = b*256 + s
    const float4 v = *reinterpret_cast<const float4*>(bump + (size_t)row * N_ + mq * 4);
    float C  = cm[0]*v.x + cm[1]*v.y + cm[2]*v.z + cm[3]*v.w;
    float Sv = sm[0]*v.x + sm[1]*v.y + sm[2]*v.z + sm[3]*v.w;
#pragma unroll
    for (int off = 1; off < 64; off <<= 1) {
      C  += __shfl_xor(C,  off, 64);
      Sv += __shfl_xor(Sv, off, 64);
    }
    float y[4];
#pragma unroll
    for (int j = 0; j < 4; ++j) y[j] = cm[j] * C + sm[j] * Sv;
    float mx = fmaxf(fmaxf(y[0], y[1]), fmaxf(y[2], y[3]));
#pragma unroll
    for (int off = 1; off < 64; off <<= 1) mx = fmaxf(mx, __shfl_xor(mx, off, 64));
    const float inv = 1.0f / mx;
    *reinterpret_cast<float4*>(out + (size_t)row * N_ + mq * 4) =
        make_float4(y[0] * inv, y[1] * inv, y[2] * inv, y[3] * inv);
  }
}

extern "C" void kernel_launch(void* const* d_in, const int* in_sizes, int n_in,
                              void* d_out, int out_size, void* d_ws, size_t ws_size,
                              hipStream_t stream) {
  const float* action = (const float*)d_in[0];
  const float* Wo     = (const float*)d_in[1];
  const float* Wa     = (const float*)d_in[2];
  float* out = (float*)d_out;
  float* rws = (float*)d_ws;   // needs 2*64*256*4 = 128 KiB (double-buffered r)

  // opt-in to >64KB dynamic LDS (idempotent, host-side, capture-safe)
  hipFuncSetAttribute(reinterpret_cast<const void*>(ring_scan_kernel),
                      hipFuncAttributeMaxDynamicSharedMemorySize, LDS_BYTES);

  void* args[] = {(void*)&action, (void*)&Wo, (void*)&Wa, (void*)&out, (void*)&rws};
  hipLaunchCooperativeKernel(reinterpret_cast<const void*>(ring_scan_kernel),
                             dim3(256), dim3(256), args,
                             (unsigned int)LDS_BYTES, stream);
}

// Round 2
// 3716.301 us; speedup vs baseline: 4.8802x; 4.8802x over previous
//
#include <hip/hip_runtime.h>
#include <math.h>

#define N_    256
#define B_    64
#define S_    256
#define A_    32
#define NSZ   4          // n-columns per block
#define BSZ   16         // batches per block
#define AROWS 33         // 32 action rows + 1 fused static row (J1*cos + Wo + J0)
#define ATS   20         // at_lds row stride (floats)
#define J0_   (-0.1f)
#define J1_   (0.1f)
#define ALPHA_ 0.15f
#define WIDTH_ 25.6f     // N / 10
#define TWO_PI 6.283185307179586f
#define RBUF  (B_ * N_)            // 16384 floats per r buffer
#define CTR_OFF (2 * RBUF)         // counters live after the two r buffers

#define WA_LDS_FLOATS (NSZ * AROWS * N_)   // 33792
#define AT_LDS_FLOATS (AROWS * ATS)        // 660
#define LDS_BYTES ((WA_LDS_FLOATS + AT_LDS_FLOATS) * 4)  // 137808 B

__device__ __forceinline__ float bumpval(float idx) {
  float d = fabsf(idx - 128.0f);
  d = fminf(d, 256.0f - d);
  return expf(-d * d / (2.0f * WIDTH_ * WIDTH_));
}

// 256 blocks x 256 threads, cooperative (co-residency only; no grid.sync).
// bgroup = bid & 3 owns 16 batches; ngroup = bid >> 2 owns 4 n-columns.
// Cross-block exchange: r-state via agent-scope (sc1/LLC) atomics; one
// monotone counter barrier per bgroup (64 blocks each). No per-step fences.
__global__ __launch_bounds__(256, 1)
void ring_scan_kernel(const float* __restrict__ action,  // [64][256][32]
                      const float* __restrict__ Wo,      // [256][256]
                      const float* __restrict__ Wa,      // [32][256][256]
                      float* __restrict__ out,           // r_hist | bump_hist
                      float* __restrict__ rws)           // ws
{
  extern __shared__ float lds[];
  float* wa_lds = lds;                  // [NSZ*AROWS][256]
  float* at_lds = lds + WA_LDS_FLOATS;  // [AROWS][ATS]

  const int tid = threadIdx.x;
  const int bid = blockIdx.x;
  const int grp = bid & 3;
  const int b0  = grp * BSZ;
  const int n0  = (bid >> 2) * NSZ;
  unsigned* ctr = reinterpret_cast<unsigned*>(rws + CTR_OFF) + grp * 32;

  // ---- Stage Wa slice + fused static row into LDS (one-time) ----
  for (int c = tid; c < NSZ * AROWS * (N_ / 4); c += 256) {
    const int rl = c >> 6;
    const int q  = c & 63;
    const int nl = rl / AROWS;
    const int a  = rl - nl * AROWS;
    const int n  = n0 + nl;
    float4 v;
    if (a < A_) {
      v = *reinterpret_cast<const float4*>(Wa + ((size_t)a * N_ + n) * N_ + q * 4);
    } else {
      const float4 wo = *reinterpret_cast<const float4*>(Wo + (size_t)n * N_ + q * 4);
      const float* wof = reinterpret_cast<const float*>(&wo);
      float tmp[4];
#pragma unroll
      for (int j = 0; j < 4; ++j) {
        const int m = q * 4 + j;
        tmp[j] = J0_ + J1_ * cosf((float)(n - m) * (TWO_PI / N_)) + wof[j];
      }
      v = make_float4(tmp[0], tmp[1], tmp[2], tmp[3]);
    }
    *reinterpret_cast<float4*>(wa_lds + rl * N_ + q * 4) = v;
  }

  const int wv = tid >> 6;     // wave id = local n
  const int mq = tid & 63;     // lane = m chunk (4 floats)
  const int nG = n0 + wv;
  const float* wrow = wa_lds + wv * AROWS * N_;
  const size_t bump_base = (size_t)B_ * S_ * N_;

  // ---- r0 entirely in registers (analytic, batch-uniform) ----
  float g[4];
  float ss = 0.0f;
#pragma unroll
  for (int j = 0; j < 4; ++j) {
    g[j] = bumpval((float)(mq * 4 + j));
    ss += g[j] * g[j];
  }
#pragma unroll
  for (int off = 1; off < 64; off <<= 1) ss += __shfl_xor(ss, off, 64);
  const float inv_norm = 1.0f / sqrtf(ss);

  float rr[BSZ][4];
#pragma unroll
  for (int b = 0; b < BSZ; ++b)
#pragma unroll
    for (int j = 0; j < 4; ++j) rr[b][j] = g[j] * inv_norm;

  float rprev = 0.0f;
  if (mq < BSZ) rprev = bumpval((float)nG) * inv_norm;  // r0[b, nG], same all b

  __syncthreads();   // wa_lds ready

  // ---- main scan: one light per-group barrier per step ----
  for (int t = 0; t < S_; ++t) {
    if (t > 0) {
      const float* rsrc = rws + (size_t)(((t - 1) & 1)) * RBUF;
#pragma unroll
      for (int b = 0; b < BSZ; ++b) {
        const float* p = rsrc + (b0 + b) * N_ + mq * 4;
#pragma unroll
        for (int j = 0; j < 4; ++j)
          rr[b][j] = __hip_atomic_load(p + j, __ATOMIC_RELAXED, __HIP_MEMORY_SCOPE_AGENT);
      }
    }

    // stage a_t transposed: at_lds[a*ATS + b]; virtual row a=32 -> 1.0
    for (int i = tid; i < BSZ * A_; i += 256) {
      const int b = i >> 5;
      const int a = i & 31;
      at_lds[a * ATS + b] = action[((size_t)(b0 + b) * S_ + t) * A_ + a];
    }
    if (tid < BSZ) at_lds[A_ * ATS + tid] = 1.0f;
    __syncthreads();

    float acc[BSZ];
#pragma unroll
    for (int b = 0; b < BSZ; ++b) acc[b] = 0.0f;

    for (int a = 0; a < AROWS; ++a) {
      const float4 w = *reinterpret_cast<const float4*>(wrow + a * N_ + mq * 4);
      const float* atp = at_lds + a * ATS;
      const float4 t0 = *reinterpret_cast<const float4*>(atp);
      const float4 t1 = *reinterpret_cast<const float4*>(atp + 4);
      const float4 t2 = *reinterpret_cast<const float4*>(atp + 8);
      const float4 t3 = *reinterpret_cast<const float4*>(atp + 12);
      float atv[BSZ];
      atv[0]=t0.x;  atv[1]=t0.y;  atv[2]=t0.z;  atv[3]=t0.w;
      atv[4]=t1.x;  atv[5]=t1.y;  atv[6]=t1.z;  atv[7]=t1.w;
      atv[8]=t2.x;  atv[9]=t2.y;  atv[10]=t2.z; atv[11]=t2.w;
      atv[12]=t3.x; atv[13]=t3.y; atv[14]=t3.z; atv[15]=t3.w;
#pragma unroll
      for (int b = 0; b < BSZ; ++b) {
        const float dd = w.x * rr[b][0] + w.y * rr[b][1] +
                         w.z * rr[b][2] + w.w * rr[b][3];
        acc[b] += atv[b] * dd;
      }
    }

#pragma unroll
    for (int off = 1; off < 64; off <<= 1) {
#pragma unroll
      for (int b = 0; b < BSZ; ++b) acc[b] += __shfl_xor(acc[b], off, 64);
    }

    if (mq < BSZ) {
      float v = acc[0];
#pragma unroll
      for (int b = 1; b < BSZ; ++b) if (mq == b) v = acc[b];
      const int bG = b0 + mq;
      const float rnew = (1.0f - ALPHA_) * rprev + ALPHA_ * fmaxf(v, 0.0f);
      rprev = rnew;
      __hip_atomic_store(rws + (size_t)(t & 1) * RBUF + bG * N_ + nG, rnew,
                         __ATOMIC_RELAXED, __HIP_MEMORY_SCOPE_AGENT);
      out[bump_base + ((size_t)bG * S_ + t) * N_ + nG] = rnew;  // normal store
    }

    // ---- per-group barrier (monotone counter, no fences) ----
    asm volatile("s_waitcnt vmcnt(0)" ::: "memory");  // sc1 stores at LLC
    __syncthreads();
    if (t < S_ - 1) {
      if (tid == 0) {
        __hip_atomic_fetch_add(ctr, 1u, __ATOMIC_RELAXED, __HIP_MEMORY_SCOPE_AGENT);
        const unsigned tgt = 64u * (unsigned)(t + 1);
        while (__hip_atomic_load(ctr, __ATOMIC_RELAXED, __HIP_MEMORY_SCOPE_AGENT) < tgt)
          __builtin_amdgcn_s_sleep(2);
      }
      __syncthreads();
    }
  }

  // ---- final barrier with real fences (bump visibility for epilogue) ----
  __threadfence();   // writeback this XCD's bump lines
  if (tid == 0) {
    __hip_atomic_fetch_add(ctr, 1u, __ATOMIC_RELAXED, __HIP_MEMORY_SCOPE_AGENT);
    while (__hip_atomic_load(ctr, __ATOMIC_RELAXED, __HIP_MEMORY_SCOPE_AGENT) < 64u * S_)
      __builtin_amdgcn_s_sleep(2);
  }
  __syncthreads();
  __threadfence();   // invalidate stale lines before reading others' bump rows

  // ---- epilogue (group-local rows): r_hist = (bump @ Wd)/rowmax, rank-2 Wd ----
  float cm[4], sm[4];
#pragma unroll
  for (int j = 0; j < 4; ++j) {
    const float ang = (float)(mq * 4 + j) * (TWO_PI / N_);
    cm[j] = cosf(ang);
    sm[j] = sinf(ang);
  }
  const float* bump = out + bump_base;
  const int k = bid >> 2;                  // 0..63 within group
  for (int it = 0; it < 16; ++it) {
    const int row_local = k * 64 + it * 4 + wv;          // 0..4095
    const int b = grp * BSZ + (row_local >> 8);
    const int s = row_local & 255;
    const size_t row = (size_t)b * S_ + s;
    const float4 v = *reinterpret_cast<const float4*>(bump + row * N_ + mq * 4);
    float C  = cm[0]*v.x + cm[1]*v.y + cm[2]*v.z + cm[3]*v.w;
    float Sv = sm[0]*v.x + sm[1]*v.y + sm[2]*v.z + sm[3]*v.w;
#pragma unroll
    for (int off = 1; off < 64; off <<= 1) {
      C  += __shfl_xor(C,  off, 64);
      Sv += __shfl_xor(Sv, off, 64);
    }
    float y[4];
#pragma unroll
    for (int j = 0; j < 4; ++j) y[j] = cm[j] * C + sm[j] * Sv;
    float mx = fmaxf(fmaxf(y[0], y[1]), fmaxf(y[2], y[3]));
#pragma unroll
    for (int off = 1; off < 64; off <<= 1) mx = fmaxf(mx, __shfl_xor(mx, off, 64));
    const float inv = 1.0f / mx;
    *reinterpret_cast<float4*>(out + row * N_ + mq * 4) =
        make_float4(y[0] * inv, y[1] * inv, y[2] * inv, y[3] * inv);
  }
}

extern "C" void kernel_launch(void* const* d_in, const int* in_sizes, int n_in,
                              void* d_out, int out_size, void* d_ws, size_t ws_size,
                              hipStream_t stream) {
  const float* action = (const float*)d_in[0];
  const float* Wo     = (const float*)d_in[1];
  const float* Wa     = (const float*)d_in[2];
  float* out = (float*)d_out;
  float* rws = (float*)d_ws;   // 2*16384 floats r dbuf + barrier counters

  // zero the barrier counters (capture-safe, stream-ordered)
  hipMemsetAsync((char*)d_ws + CTR_OFF * sizeof(float), 0, 512, stream);

  hipFuncSetAttribute(reinterpret_cast<const void*>(ring_scan_kernel),
                      hipFuncAttributeMaxDynamicSharedMemorySize, LDS_BYTES);

  void* args[] = {(void*)&action, (void*)&Wo, (void*)&Wa, (void*)&out, (void*)&rws};
  hipLaunchCooperativeKernel(reinterpret_cast<const void*>(ring_scan_kernel),
                             dim3(256), dim3(256), args,
                             (unsigned int)LDS_BYTES, stream);
}

// Round 3
// 2659.915 us; speedup vs baseline: 6.8183x; 1.3972x over previous
//
#include <hip/hip_runtime.h>
#include <math.h>

#define N_    256
#define B_    64
#define S_    256
#define A_    32
#define NSZ   4          // n-columns per block
#define BSZ   16         // batches per block (split 8+8 across wave halves)
#define AROWS 33         // 32 action rows + 1 fused static row (J1*cos + Wo + J0)
#define ATS   20         // at_lds row stride (floats)
#define J0_   (-0.1f)
#define J1_   (0.1f)
#define ALPHA_ 0.15f
#define WIDTH_ 25.6f     // N / 10
#define TWO_PI 6.283185307179586f
#define RBUF  (N_ * B_)            // 16384 floats per r buffer, layout [n][b]
#define FLAG_OFF (2 * RBUF)        // flags (4 groups x 64 uint) after r dbuf

#define WA_LDS_FLOATS (NSZ * AROWS * N_)   // 33792
#define AT_LDS_FLOATS (2 * AROWS * ATS)    // 1320 (double-buffered a_t)
#define LDS_BYTES ((WA_LDS_FLOATS + AT_LDS_FLOATS) * 4)  // 140448 B

// coherent (LLC) 16B load: bypass potentially-stale per-XCD L2
#define LOADX4(dst, p) \
  asm volatile("global_load_dwordx4 %0, %1, off sc0 sc1" \
               : "=v"(dst) : "v"(p) : "memory")

__device__ __forceinline__ float bumpval(float idx) {
  float d = fabsf(idx - 128.0f);
  d = fminf(d, 256.0f - d);
  return expf(-d * d / (2.0f * WIDTH_ * WIDTH_));
}

// 256 blocks x 512 threads, cooperative (co-residency; no grid.sync).
// grp = bid & 3 owns 16 batches; ngroup = bid >> 2 owns 4 n-columns.
// Waves 0-3: n = n0+wv, batches b0..b0+7; waves 4-7: n = n0+(wv-4), b0+8..b0+15.
// Cross-block r exchange at LLC via sc1; per-group flag-array barrier (no RMW).
__global__ __launch_bounds__(512, 1)
void ring_scan_kernel(const float* __restrict__ action,  // [64][256][32]
                      const float* __restrict__ Wo,      // [256][256]
                      const float* __restrict__ Wa,      // [32][256][256]
                      float* __restrict__ out,           // r_hist | bump_hist
                      float* __restrict__ rws)           // ws
{
  extern __shared__ float lds[];
  float* wa_lds = lds;                  // [NSZ*AROWS][256]
  float* at_lds = lds + WA_LDS_FLOATS;  // 2 x [AROWS][ATS]

  const int tid = threadIdx.x;
  const int bid = blockIdx.x;
  const int grp = bid & 3;
  const int b0  = grp * BSZ;
  const int n0  = (bid >> 2) * NSZ;
  unsigned* flags = reinterpret_cast<unsigned*>(rws + FLAG_OFF) + grp * 64;
  const int myflag = bid >> 2;          // 0..63 within group

  // ---- Stage Wa slice + fused static row into LDS (one-time) ----
  for (int c = tid; c < NSZ * AROWS * (N_ / 4); c += 512) {
    const int rl = c >> 6;
    const int q  = c & 63;
    const int nl = rl / AROWS;
    const int a  = rl - nl * AROWS;
    const int n  = n0 + nl;
    float4 v;
    if (a < A_) {
      v = *reinterpret_cast<const float4*>(Wa + ((size_t)a * N_ + n) * N_ + q * 4);
    } else {
      const float4 wo = *reinterpret_cast<const float4*>(Wo + (size_t)n * N_ + q * 4);
      const float* wof = reinterpret_cast<const float*>(&wo);
      float tmp[4];
#pragma unroll
      for (int j = 0; j < 4; ++j) {
        const int m = q * 4 + j;
        tmp[j] = J0_ + J1_ * cosf((float)(n - m) * (TWO_PI / N_)) + wof[j];
      }
      v = make_float4(tmp[0], tmp[1], tmp[2], tmp[3]);
    }
    *reinterpret_cast<float4*>(wa_lds + rl * N_ + q * 4) = v;
  }

  const int wv    = tid >> 6;          // 0..7
  const int mq    = tid & 63;
  const int nloc  = wv & 3;
  const int nG    = n0 + nloc;
  const int bhalf = (wv >> 2) * 8;     // 0 or 8
  const int bb0   = b0 + bhalf;
  const float* wrow = wa_lds + nloc * AROWS * N_;
  const size_t bump_base = (size_t)B_ * S_ * N_;

  // ---- stage a_t(0) into buffer 0 ----
  {
    const int b = tid >> 5, a = tid & 31;            // 512 threads = 16b x 32a
    at_lds[a * ATS + b] = action[((size_t)(b0 + b) * S_) * A_ + a];
    if (tid < BSZ) at_lds[A_ * ATS + tid] = 1.0f;
  }

  // ---- r0 in registers (analytic, batch-uniform) ----
  float g[4];
  float ss = 0.0f;
#pragma unroll
  for (int j = 0; j < 4; ++j) {
    g[j] = bumpval((float)(mq * 4 + j));
    ss += g[j] * g[j];
  }
#pragma unroll
  for (int off = 1; off < 64; off <<= 1) ss += __shfl_xor(ss, off, 64);
  const float inv_norm = 1.0f / sqrtf(ss);

  float rr[8][4];
#pragma unroll
  for (int b = 0; b < 8; ++b)
#pragma unroll
    for (int j = 0; j < 4; ++j) rr[b][j] = g[j] * inv_norm;

  float rprev = 0.0f;
  if (mq < 8) rprev = bumpval((float)nG) * inv_norm;

  __syncthreads();   // wa_lds + at(0) ready

  // ---- main scan ----
  for (int t = 0; t < S_; ++t) {
    const float* atb = at_lds + (t & 1) * (AROWS * ATS);

    float acc[8];
#pragma unroll
    for (int b = 0; b < 8; ++b) acc[b] = 0.0f;

    for (int a = 0; a < AROWS; ++a) {
      const float4 w = *reinterpret_cast<const float4*>(wrow + a * N_ + mq * 4);
      const float* atp = atb + a * ATS + bhalf;
      const float4 t0 = *reinterpret_cast<const float4*>(atp);
      const float4 t1 = *reinterpret_cast<const float4*>(atp + 4);
      float atv[8];
      atv[0]=t0.x; atv[1]=t0.y; atv[2]=t0.z; atv[3]=t0.w;
      atv[4]=t1.x; atv[5]=t1.y; atv[6]=t1.z; atv[7]=t1.w;
#pragma unroll
      for (int b = 0; b < 8; ++b) {
        const float dd = w.x * rr[b][0] + w.y * rr[b][1] +
                         w.z * rr[b][2] + w.w * rr[b][3];
        acc[b] += atv[b] * dd;
      }
    }

#pragma unroll
    for (int off = 1; off < 64; off <<= 1) {
#pragma unroll
      for (int b = 0; b < 8; ++b) acc[b] += __shfl_xor(acc[b], off, 64);
    }

    if (mq < 8) {
      float v = acc[0];
#pragma unroll
      for (int b = 1; b < 8; ++b) if (mq == b) v = acc[b];
      const int bG = bb0 + mq;
      const float rnew = (1.0f - ALPHA_) * rprev + ALPHA_ * fmaxf(v, 0.0f);
      rprev = rnew;
      // [n][b] layout: lanes 0..7 of the two wave-halves fill one 64B line
      __hip_atomic_store(rws + (size_t)(t & 1) * RBUF + nG * B_ + bG, rnew,
                         __ATOMIC_RELAXED, __HIP_MEMORY_SCOPE_AGENT);
      out[bump_base + ((size_t)bG * S_ + t) * N_ + nG] = rnew;
    }

    if (t == S_ - 1) break;

    asm volatile("s_waitcnt vmcnt(0)" ::: "memory");  // r stores acked at LLC
    __syncthreads();
    if (tid == 0)
      __hip_atomic_store(&flags[myflag], (unsigned)(t + 1),
                         __ATOMIC_RELAXED, __HIP_MEMORY_SCOPE_AGENT);

    // stage a_t(t+1) into the other buffer — overlaps other blocks' arrival
    {
      float* atn = at_lds + ((t + 1) & 1) * (AROWS * ATS);
      const int b = tid >> 5, a = tid & 31;
      atn[a * ATS + b] = action[((size_t)(b0 + b) * S_ + (t + 1)) * A_ + a];
      if (tid < BSZ) atn[A_ * ATS + tid] = 1.0f;
    }

    if (wv == 0) {   // one wave polls: 64 lanes cover the 64 flags
      const unsigned tgt = (unsigned)(t + 1);
      while (true) {
        const unsigned f = __hip_atomic_load(&flags[mq], __ATOMIC_RELAXED,
                                             __HIP_MEMORY_SCOPE_AGENT);
        if (__all(f >= tgt)) break;
        __builtin_amdgcn_s_sleep(2);
      }
    }
    __syncthreads();

    // reload r(t) coherently: 8 x dwordx4 per lane, [n][b] layout
    {
      const float* rsrc = rws + (size_t)(t & 1) * RBUF;
      const float* pj0 = rsrc + (mq * 4 + 0) * B_ + bb0;
      const float* pj1 = rsrc + (mq * 4 + 1) * B_ + bb0;
      const float* pj2 = rsrc + (mq * 4 + 2) * B_ + bb0;
      const float* pj3 = rsrc + (mq * 4 + 3) * B_ + bb0;
      float4 q00, q01, q10, q11, q20, q21, q30, q31;
      LOADX4(q00, pj0); LOADX4(q01, pj0 + 4);
      LOADX4(q10, pj1); LOADX4(q11, pj1 + 4);
      LOADX4(q20, pj2); LOADX4(q21, pj2 + 4);
      LOADX4(q30, pj3); LOADX4(q31, pj3 + 4);
      asm volatile("s_waitcnt vmcnt(0)" ::: "memory");
      __builtin_amdgcn_sched_barrier(0);
      rr[0][0]=q00.x; rr[1][0]=q00.y; rr[2][0]=q00.z; rr[3][0]=q00.w;
      rr[4][0]=q01.x; rr[5][0]=q01.y; rr[6][0]=q01.z; rr[7][0]=q01.w;
      rr[0][1]=q10.x; rr[1][1]=q10.y; rr[2][1]=q10.z; rr[3][1]=q10.w;
      rr[4][1]=q11.x; rr[5][1]=q11.y; rr[6][1]=q11.z; rr[7][1]=q11.w;
      rr[0][2]=q20.x; rr[1][2]=q20.y; rr[2][2]=q20.z; rr[3][2]=q20.w;
      rr[4][2]=q21.x; rr[5][2]=q21.y; rr[6][2]=q21.z; rr[7][2]=q21.w;
      rr[0][3]=q30.x; rr[1][3]=q30.y; rr[2][3]=q30.z; rr[3][3]=q30.w;
      rr[4][3]=q31.x; rr[5][3]=q31.y; rr[6][3]=q31.z; rr[7][3]=q31.w;
    }
  }

  // ---- final barrier with L2 writeback/invalidate (bump visibility) ----
  __threadfence();
  __syncthreads();
  if (tid == 0)
    __hip_atomic_store(&flags[myflag], 256u,
                       __ATOMIC_RELAXED, __HIP_MEMORY_SCOPE_AGENT);
  if (wv == 0) {
    while (true) {
      const unsigned f = __hip_atomic_load(&flags[mq], __ATOMIC_RELAXED,
                                           __HIP_MEMORY_SCOPE_AGENT);
      if (__all(f >= 256u)) break;
      __builtin_amdgcn_s_sleep(2);
    }
  }
  __syncthreads();
  __threadfence();

  // ---- epilogue (group-local rows): r_hist = (bump @ Wd)/rowmax, rank-2 Wd ----
  float cm[4], sm[4];
#pragma unroll
  for (int j = 0; j < 4; ++j) {
    const float ang = (float)(mq * 4 + j) * (TWO_PI / N_);
    cm[j] = cosf(ang);
    sm[j] = sinf(ang);
  }
  const float* bump = out + bump_base;
  const int k = bid >> 2;
  for (int it = 0; it < 8; ++it) {
    const int row_local = k * 64 + it * 8 + wv;           // 0..4095
    const int b = grp * BSZ + (row_local >> 8);
    const int s = row_local & 255;
    const size_t row = (size_t)b * S_ + s;
    const float4 v = *reinterpret_cast<const float4*>(bump + row * N_ + mq * 4);
    float C  = cm[0]*v.x + cm[1]*v.y + cm[2]*v.z + cm[3]*v.w;
    float Sv = sm[0]*v.x + sm[1]*v.y + sm[2]*v.z + sm[3]*v.w;
#pragma unroll
    for (int off = 1; off < 64; off <<= 1) {
      C  += __shfl_xor(C,  off, 64);
      Sv += __shfl_xor(Sv, off, 64);
    }
    float y[4];
#pragma unroll
    for (int j = 0; j < 4; ++j) y[j] = cm[j] * C + sm[j] * Sv;
    float mx = fmaxf(fmaxf(y[0], y[1]), fmaxf(y[2], y[3]));
#pragma unroll
    for (int off = 1; off < 64; off <<= 1) mx = fmaxf(mx, __shfl_xor(mx, off, 64));
    const float inv = 1.0f / mx;
    *reinterpret_cast<float4*>(out + row * N_ + mq * 4) =
        make_float4(y[0] * inv, y[1] * inv, y[2] * inv, y[3] * inv);
  }
}

extern "C" void kernel_launch(void* const* d_in, const int* in_sizes, int n_in,
                              void* d_out, int out_size, void* d_ws, size_t ws_size,
                              hipStream_t stream) {
  const float* action = (const float*)d_in[0];
  const float* Wo     = (const float*)d_in[1];
  const float* Wa     = (const float*)d_in[2];
  float* out = (float*)d_out;
  float* rws = (float*)d_ws;   // 2*16384 floats r dbuf + 1KB flags

  // zero the barrier flags every launch (graph-captured, stream-ordered)
  hipMemsetAsync((char*)d_ws + FLAG_OFF * sizeof(float), 0, 1024, stream);

  hipFuncSetAttribute(reinterpret_cast<const void*>(ring_scan_kernel),
                      hipFuncAttributeMaxDynamicSharedMemorySize, LDS_BYTES);

  void* args[] = {(void*)&action, (void*)&Wo, (void*)&Wa, (void*)&out, (void*)&rws};
  hipLaunchCooperativeKernel(reinterpret_cast<const void*>(ring_scan_kernel),
                             dim3(256), dim3(512), args,
                             (unsigned int)LDS_BYTES, stream);
}

// Round 7
// 2622.686 us; speedup vs baseline: 6.9151x; 1.0142x over previous
//
#include <hip/hip_runtime.h>
#include <math.h>

#define N_    256
#define B_    64
#define S_    256
#define A_    32
#define NSZ   8           // n-columns per block (32 blocks x 8n per group)
#define BSZ   8           // batches per group
#define AROWS 33          // 32 action rows + 1 fused static row
#define LROWS 19          // LDS rows per n: Wa[0..17] + static row (lds idx 18)
#define SROWS 14          // streamed-from-L2 rows: Wa[18..31] (read-only => safe)
#define ATS   12          // at_lds row stride (floats)
#define J0_   (-0.1f)
#define J1_   (0.1f)
#define ALPHA_ 0.15f
#define WIDTH_ 25.6f
#define TWO_PI 6.283185307179586f

// ws floats: r dbuf [8 grp][2][256 n][8 b] = 32768, then flags 8*32 uint
#define RGRP      (2 * N_ * BSZ)          // 4096 floats per group
#define RPAR      (N_ * BSZ)              // 2048 floats per parity
#define FLAG_OFF  (8 * RGRP)              // 32768

#define WA_LDS_FLOATS (NSZ * LROWS * N_)  // 38912
#define AT_LDS_FLOATS (2 * AROWS * ATS)   // 792
#define LDS_BYTES ((WA_LDS_FLOATS + AT_LDS_FLOATS) * 4)  // 158816

#define NN ((size_t)N_ * N_)

// device-coherent (LLC) 16B load — proven in round 3
#define LOADX4_COH(dst, p) \
  asm volatile("global_load_dwordx4 %0, %1, off sc0 sc1" \
               : "=v"(dst) : "v"(p) : "memory")
// plain 16B load (read-only Wa streaming, L2-cached)
#define LOADX4(dst, p) \
  asm volatile("global_load_dwordx4 %0, %1, off" : "=v"(dst) : "v"(p) : "memory")
#define WAIT_VM0() asm volatile("s_waitcnt vmcnt(0)" ::: "memory")

// per-row FMA: 8 batches, a_t broadcast from LDS (wave-uniform)
#define ROWFMA(wvec, a_idx) do {                                              \
    const float* atp_ = atb + (a_idx) * ATS;                                  \
    const float4 t0_ = *reinterpret_cast<const float4*>(atp_);                \
    const float4 t1_ = *reinterpret_cast<const float4*>(atp_ + 4);            \
    const float at8_[8] = {t0_.x,t0_.y,t0_.z,t0_.w,t1_.x,t1_.y,t1_.z,t1_.w};  \
    _Pragma("unroll")                                                         \
    for (int b_ = 0; b_ < 8; ++b_) {                                          \
      const float dd_ = (wvec).x*rr[b_][0] + (wvec).y*rr[b_][1] +             \
                        (wvec).z*rr[b_][2] + (wvec).w*rr[b_][3];              \
      acc[b_] += at8_[b_] * dd_;                                              \
    }                                                                         \
  } while (0)

// streamed row: literal-count vmcnt wait, then FMA (all tokens static)
#define STREAMROW(idx, var, cnt) do {                                 \
    asm volatile("s_waitcnt vmcnt(" #cnt ")" ::: "memory");           \
    __builtin_amdgcn_sched_barrier(0);                                \
    ROWFMA(var, 18 + idx);                                            \
  } while (0)

__device__ __forceinline__ float bumpval(float idx) {
  float d = fabsf(idx - 128.0f);
  d = fminf(d, 256.0f - d);
  return expf(-d * d / (2.0f * WIDTH_ * WIDTH_));
}

// 256 blocks x 512 threads, cooperative (co-residency => barrier can't starve).
// grp = bid & 7 owns batches 8*grp..8*grp+7; rank = bid >> 3 owns n = 8r..8r+7
// (wave w -> n0+w). Cross-block r exchange via AGENT atomics / sc0sc1 loads
// (LLC-coherent, placement-independent — round-3-proven primitives).
__global__ __launch_bounds__(512, 1)
void ring_scan_kernel(const float* __restrict__ action,  // [64][256][32]
                      const float* __restrict__ Wo,      // [256][256]
                      const float* __restrict__ Wa,      // [32][256][256]
                      float* __restrict__ out,           // r_hist | bump_hist
                      float* __restrict__ rws)
{
  extern __shared__ float lds[];
  float* wa_lds = lds;                      // [NSZ][LROWS][256]
  float* at_lds = lds + WA_LDS_FLOATS;      // [2][AROWS][ATS]

  const int tid  = threadIdx.x;
  const int bid  = blockIdx.x;
  const int grp  = bid & 7;
  const int rank = bid >> 3;                // 0..31
  const int b0   = grp * BSZ;
  const int n0   = rank * NSZ;
  float*    rbase = rws + grp * RGRP;
  unsigned* flags = reinterpret_cast<unsigned*>(rws + FLAG_OFF) + grp * 32;

  // ---- stage LDS: Wa rows 0..17 + fused static row (idx 18) per n ----
  for (int c = tid; c < NSZ * LROWS * (N_ / 4); c += 512) {
    const int rl = c >> 6;            // nl*LROWS + a
    const int q  = c & 63;
    const int nl = rl / LROWS;
    const int a  = rl - nl * LROWS;
    const int n  = n0 + nl;
    float4 v;
    if (a < 18) {
      v = *reinterpret_cast<const float4*>(Wa + ((size_t)a * N_ + n) * N_ + q * 4);
    } else {
      const float4 wo = *reinterpret_cast<const float4*>(Wo + (size_t)n * N_ + q * 4);
      const float* wof = reinterpret_cast<const float*>(&wo);
      float tmp[4];
#pragma unroll
      for (int j = 0; j < 4; ++j) {
        const int m = q * 4 + j;
        tmp[j] = J0_ + J1_ * cosf((float)(n - m) * (TWO_PI / N_)) + wof[j];
      }
      v = make_float4(tmp[0], tmp[1], tmp[2], tmp[3]);
    }
    *reinterpret_cast<float4*>(wa_lds + rl * N_ + q * 4) = v;
  }
  // a_t virtual row (a=32) = 1.0, both buffers
  if (tid < 16)
    at_lds[(tid >> 3) * (AROWS * ATS) + A_ * ATS + (tid & 7)] = 1.0f;
  // a_t(0) into buffer 0: 8 b x 32 a
  if (tid < 256) {
    const int b = tid >> 5, a = tid & 31;
    at_lds[a * ATS + b] = action[((size_t)(b0 + b) * S_) * A_ + a];
  }

  const int wv = tid >> 6;
  const int mq = tid & 63;
  const int nG = n0 + wv;
  const float* wrow = wa_lds + wv * (LROWS * N_);
  const size_t bump_base = (size_t)B_ * S_ * N_;

  // ---- r0 in registers ----
  float g[4]; float ss = 0.0f;
#pragma unroll
  for (int j = 0; j < 4; ++j) { g[j] = bumpval((float)(mq * 4 + j)); ss += g[j] * g[j]; }
#pragma unroll
  for (int off = 1; off < 64; off <<= 1) ss += __shfl_xor(ss, off, 64);
  const float inv_norm = 1.0f / sqrtf(ss);

  float rr[8][4];
#pragma unroll
  for (int b = 0; b < 8; ++b)
#pragma unroll
    for (int j = 0; j < 4; ++j) rr[b][j] = g[j] * inv_norm;
  float rprev = (mq < 8) ? bumpval((float)nG) * inv_norm : 0.0f;

  __syncthreads();   // LDS ready
  WAIT_VM0();        // clean vmcnt baseline for counted waits at t=0

  // ---- main scan ----
  for (int t = 0; t < S_; ++t) {
    const float* atb = at_lds + (t & 1) * (AROWS * ATS);

    if (t > 0) {   // reload r(t) — contiguous [n][8b], 128B per lane
      const float* p = rbase + ((t - 1) & 1) * RPAR + mq * 32;
      float4 q00,q01,q10,q11,q20,q21,q30,q31;
      LOADX4_COH(q00, p);      LOADX4_COH(q01, p + 4);
      LOADX4_COH(q10, p + 8);  LOADX4_COH(q11, p + 12);
      LOADX4_COH(q20, p + 16); LOADX4_COH(q21, p + 20);
      LOADX4_COH(q30, p + 24); LOADX4_COH(q31, p + 28);
      WAIT_VM0();
      __builtin_amdgcn_sched_barrier(0);
      rr[0][0]=q00.x; rr[1][0]=q00.y; rr[2][0]=q00.z; rr[3][0]=q00.w;
      rr[4][0]=q01.x; rr[5][0]=q01.y; rr[6][0]=q01.z; rr[7][0]=q01.w;
      rr[0][1]=q10.x; rr[1][1]=q10.y; rr[2][1]=q10.z; rr[3][1]=q10.w;
      rr[4][1]=q11.x; rr[5][1]=q11.y; rr[6][1]=q11.z; rr[7][1]=q11.w;
      rr[0][2]=q20.x; rr[1][2]=q20.y; rr[2][2]=q20.z; rr[3][2]=q20.w;
      rr[4][2]=q21.x; rr[5][2]=q21.y; rr[6][2]=q21.z; rr[7][2]=q21.w;
      rr[0][3]=q30.x; rr[1][3]=q30.y; rr[2][3]=q30.z; rr[3][3]=q30.w;
      rr[4][3]=q31.x; rr[5][3]=q31.y; rr[6][3]=q31.z; rr[7][3]=q31.w;
    }

    // issue the 14 streamed Wa rows (read-only, own-XCD L2 cached)
    float4 sw0,sw1,sw2,sw3,sw4,sw5,sw6,sw7,sw8,sw9,sw10,sw11,sw12,sw13;
    {
      const float* wg = Wa + ((size_t)18 * N_ + nG) * N_ + mq * 4;
      LOADX4(sw0,  wg);           LOADX4(sw1,  wg + 1*NN);
      LOADX4(sw2,  wg + 2*NN);    LOADX4(sw3,  wg + 3*NN);
      LOADX4(sw4,  wg + 4*NN);    LOADX4(sw5,  wg + 5*NN);
      LOADX4(sw6,  wg + 6*NN);    LOADX4(sw7,  wg + 7*NN);
      LOADX4(sw8,  wg + 8*NN);    LOADX4(sw9,  wg + 9*NN);
      LOADX4(sw10, wg + 10*NN);   LOADX4(sw11, wg + 11*NN);
      LOADX4(sw12, wg + 12*NN);   LOADX4(sw13, wg + 13*NN);
    }

    float acc[8];
#pragma unroll
    for (int b = 0; b < 8; ++b) acc[b] = 0.0f;

#pragma unroll
    for (int a = 0; a < LROWS; ++a) {       // LDS rows; idx 18 = static (atv=1)
      const float4 w = *reinterpret_cast<const float4*>(wrow + a * N_ + mq * 4);
      ROWFMA(w, (a < 18) ? a : 32);
    }
    STREAMROW(0,  sw0,  13);  STREAMROW(1,  sw1,  12);
    STREAMROW(2,  sw2,  11);  STREAMROW(3,  sw3,  10);
    STREAMROW(4,  sw4,   9);  STREAMROW(5,  sw5,   8);
    STREAMROW(6,  sw6,   7);  STREAMROW(7,  sw7,   6);
    STREAMROW(8,  sw8,   5);  STREAMROW(9,  sw9,   4);
    STREAMROW(10, sw10,  3);  STREAMROW(11, sw11,  2);
    STREAMROW(12, sw12,  1);  STREAMROW(13, sw13,  0);

#pragma unroll
    for (int off = 1; off < 64; off <<= 1) {
#pragma unroll
      for (int b = 0; b < 8; ++b) acc[b] += __shfl_xor(acc[b], off, 64);
    }

    float rnew = 0.0f;
    if (mq < 8) {
      float v = acc[0];
#pragma unroll
      for (int b = 1; b < 8; ++b) if (mq == b) v = acc[b];
      rnew = (1.0f - ALPHA_) * rprev + ALPHA_ * fmaxf(v, 0.0f);
      rprev = rnew;
      __hip_atomic_store(rbase + (t & 1) * RPAR + nG * BSZ + mq, rnew,
                         __ATOMIC_RELAXED, __HIP_MEMORY_SCOPE_AGENT);
    }

    if (t == S_ - 1) {
      if (mq < 8)
        out[bump_base + ((size_t)(b0 + mq) * S_ + t) * N_ + nG] = rnew;
      break;
    }

    WAIT_VM0();           // r stores acked at LLC (per wave)
    __syncthreads();      // all waves drained
    if (tid == 0)
      __hip_atomic_store(&flags[rank], (unsigned)(t + 1),
                         __ATOMIC_RELAXED, __HIP_MEMORY_SCOPE_AGENT);

    // bump store + next a_t staging overlap the barrier window
    if (mq < 8)
      out[bump_base + ((size_t)(b0 + mq) * S_ + t) * N_ + nG] = rnew;
    if (tid < 256) {
      const int b = tid >> 5, a = tid & 31;
      at_lds[((t + 1) & 1) * (AROWS * ATS) + a * ATS + b] =
          action[((size_t)(b0 + b) * S_ + (t + 1)) * A_ + a];
    }

    if (wv == 0) {        // wave 0 polls the 32 group flags (lanes 0-31 live)
      const unsigned tgt = (unsigned)(t + 1);
      while (true) {
        const unsigned f = __hip_atomic_load(&flags[mq & 31], __ATOMIC_RELAXED,
                                             __HIP_MEMORY_SCOPE_AGENT);
        if (__all((int)(f >= tgt))) break;
        __builtin_amdgcn_s_sleep(2);
      }
    }
    __syncthreads();
  }

  // ---- final barrier with device fences (bump visibility for epilogue) ----
  __threadfence();
  __syncthreads();
  if (tid == 0)
    __hip_atomic_store(&flags[rank], 256u, __ATOMIC_RELAXED,
                       __HIP_MEMORY_SCOPE_AGENT);
  if (wv == 0) {
    while (true) {
      const unsigned f = __hip_atomic_load(&flags[mq & 31], __ATOMIC_RELAXED,
                                           __HIP_MEMORY_SCOPE_AGENT);
      if (__all((int)(f >= 256u))) break;
      __builtin_amdgcn_s_sleep(2);
    }
  }
  __syncthreads();
  __threadfence();

  // ---- epilogue: rank-2 Wd, this group's rows only ----
  float cm[4], sm[4];
#pragma unroll
  for (int j = 0; j < 4; ++j) {
    const float ang = (float)(mq * 4 + j) * (TWO_PI / N_);
    cm[j] = cosf(ang);
    sm[j] = sinf(ang);
  }
  const float* bump = out + bump_base;
  for (int it = 0; it < 8; ++it) {
    const int row_local = rank * 64 + it * 8 + wv;      // 0..2047 per group
    const int b = b0 + (row_local >> 8);
    const int s = row_local & 255;
    const size_t row = (size_t)b * S_ + s;
    const float4 v = *reinterpret_cast<const float4*>(bump + row * N_ + mq * 4);
    float C  = cm[0]*v.x + cm[1]*v.y + cm[2]*v.z + cm[3]*v.w;
    float Sv = sm[0]*v.x + sm[1]*v.y + sm[2]*v.z + sm[3]*v.w;
#pragma unroll
    for (int off = 1; off < 64; off <<= 1) {
      C  += __shfl_xor(C,  off, 64);
      Sv += __shfl_xor(Sv, off, 64);
    }
    float y[4];
#pragma unroll
    for (int j = 0; j < 4; ++j) y[j] = cm[j] * C + sm[j] * Sv;
    float mx = fmaxf(fmaxf(y[0], y[1]), fmaxf(y[2], y[3]));
#pragma unroll
    for (int off = 1; off < 64; off <<= 1) mx = fmaxf(mx, __shfl_xor(mx, off, 64));
    const float inv = 1.0f / mx;
    *reinterpret_cast<float4*>(out + row * N_ + mq * 4) =
        make_float4(y[0] * inv, y[1] * inv, y[2] * inv, y[3] * inv);
  }
}

extern "C" void kernel_launch(void* const* d_in, const int* in_sizes, int n_in,
                              void* d_out, int out_size, void* d_ws, size_t ws_size,
                              hipStream_t stream) {
  const float* action = (const float*)d_in[0];
  const float* Wo     = (const float*)d_in[1];
  const float* Wa     = (const float*)d_in[2];
  float* out = (float*)d_out;
  float* rws = (float*)d_ws;

  // zero the barrier flags each launch (stream-ordered, capture-safe)
  (void)hipMemsetAsync((char*)d_ws + FLAG_OFF * sizeof(float), 0, 1024, stream);

  (void)hipFuncSetAttribute(reinterpret_cast<const void*>(ring_scan_kernel),
                            hipFuncAttributeMaxDynamicSharedMemorySize, LDS_BYTES);

  void* args[] = {(void*)&action, (void*)&Wo, (void*)&Wa, (void*)&out, (void*)&rws};
  (void)hipLaunchCooperativeKernel(reinterpret_cast<const void*>(ring_scan_kernel),
                                   dim3(256), dim3(512), args,
                                   (unsigned int)LDS_BYTES, stream);
}

// Round 8
// 1559.899 us; speedup vs baseline: 11.6265x; 1.6813x over previous
//
#include <hip/hip_runtime.h>
#include <math.h>

#define N_    256
#define B_    64
#define S_    256
#define A_    32
#define NSZ   8           // n-columns per block (32 blocks x 8n per group)
#define BSZ   8           // batches per group
#define AROWS 33          // 32 action rows + 1 fused static row
#define LROWS 18          // LDS rows per n: Wa[0..16] + static row (lds idx 17)
#define RROWS 15          // register-pinned rows: Wa[17..31] (static data!)
#define ATS   12          // at_lds row stride (floats)
#define J0_   (-0.1f)
#define J1_   (0.1f)
#define ALPHA_ 0.15f
#define WIDTH_ 25.6f
#define TWO_PI 6.283185307179586f

// ws floats: r dbuf [8 grp][2][8 b][256 n] = 32768, then flags 8*32 uint
#define RPAR      (BSZ * N_)              // 2048 floats per parity, [b][n]
#define RGRP      (2 * RPAR)
#define FLAG_OFF  (8 * RGRP)              // 32768

#define WA_LDS_FLOATS (NSZ * LROWS * N_)  // 36864
#define AT_LDS_FLOATS (2 * AROWS * ATS)   // 792
#define RLDS_FLOATS   (RPAR)              // 2048
#define LDS_BYTES ((WA_LDS_FLOATS + AT_LDS_FLOATS + RLDS_FLOATS) * 4) // 158816

#define NN ((size_t)N_ * N_)

// device-coherent (LLC) 16B load — round-3-proven
#define LOADX4_COH(dst, p) \
  asm volatile("global_load_dwordx4 %0, %1, off sc0 sc1" \
               : "=v"(dst) : "v"(p) : "memory")
// plain cached 16B load (read-only Wa)
#define LOADX4(dst, p) \
  asm volatile("global_load_dwordx4 %0, %1, off" : "=v"(dst) : "v"(p) : "memory")
#define WAIT_VM0() asm volatile("s_waitcnt vmcnt(0)" ::: "memory")

// per-row FMA: 8 batches, a_t broadcast from LDS (wave-uniform)
#define ROWFMA(wvec, a_idx) do {                                              \
    const float* atp_ = atb + (a_idx) * ATS;                                  \
    const float4 t0_ = *reinterpret_cast<const float4*>(atp_);                \
    const float4 t1_ = *reinterpret_cast<const float4*>(atp_ + 4);            \
    const float at8_[8] = {t0_.x,t0_.y,t0_.z,t0_.w,t1_.x,t1_.y,t1_.z,t1_.w};  \
    _Pragma("unroll")                                                         \
    for (int b_ = 0; b_ < 8; ++b_) {                                          \
      const float dd_ = (wvec).x*rr[b_][0] + (wvec).y*rr[b_][1] +             \
                        (wvec).z*rr[b_][2] + (wvec).w*rr[b_][3];              \
      acc[b_] += at8_[b_] * dd_;                                              \
    }                                                                         \
  } while (0)

__device__ __forceinline__ float bumpval(float idx) {
  float d = fabsf(idx - 128.0f);
  d = fminf(d, 256.0f - d);
  return expf(-d * d / (2.0f * WIDTH_ * WIDTH_));
}

// 256 blocks x 512 threads, cooperative. grp = bid & 7 owns batches 8g..8g+7;
// rank = bid >> 3 owns n = 8r..8r+7 (wave w -> n0+w). Weights: 18 rows/n in
// LDS + 15 rows/n pinned in VGPRs (Wa is constant!). r exchange at LLC
// (AGENT atomics / sc0sc1), staged through LDS once per block per step.
__global__ __launch_bounds__(512, 1)
void ring_scan_kernel(const float* __restrict__ action,  // [64][256][32]
                      const float* __restrict__ Wo,      // [256][256]
                      const float* __restrict__ Wa,      // [32][256][256]
                      float* __restrict__ out,           // r_hist | bump_hist
                      float* __restrict__ rws)
{
  extern __shared__ float lds[];
  float* wa_lds = lds;                                   // [NSZ][LROWS][256]
  float* at_lds = lds + WA_LDS_FLOATS;                   // [2][AROWS][ATS]
  float* r_lds  = lds + WA_LDS_FLOATS + AT_LDS_FLOATS;   // [8 b][256 n]

  const int tid  = threadIdx.x;
  const int bid  = blockIdx.x;
  const int grp  = bid & 7;
  const int rank = bid >> 3;                // 0..31
  const int b0   = grp * BSZ;
  const int n0   = rank * NSZ;
  float*    rbase = rws + grp * RGRP;
  unsigned* flags = reinterpret_cast<unsigned*>(rws + FLAG_OFF) + grp * 32;

  // ---- stage LDS: Wa rows 0..16 + fused static row (idx 17) per n ----
  for (int c = tid; c < NSZ * LROWS * (N_ / 4); c += 512) {
    const int rl = c >> 6;            // nl*LROWS + a
    const int q  = c & 63;
    const int nl = rl / LROWS;
    const int a  = rl - nl * LROWS;
    const int n  = n0 + nl;
    float4 v;
    if (a < 17) {
      v = *reinterpret_cast<const float4*>(Wa + ((size_t)a * N_ + n) * N_ + q * 4);
    } else {
      const float4 wo = *reinterpret_cast<const float4*>(Wo + (size_t)n * N_ + q * 4);
      const float* wof = reinterpret_cast<const float*>(&wo);
      float tmp[4];
#pragma unroll
      for (int j = 0; j < 4; ++j) {
        const int m = q * 4 + j;
        tmp[j] = J0_ + J1_ * cosf((float)(n - m) * (TWO_PI / N_)) + wof[j];
      }
      v = make_float4(tmp[0], tmp[1], tmp[2], tmp[3]);
    }
    *reinterpret_cast<float4*>(wa_lds + rl * N_ + q * 4) = v;
  }
  // a_t virtual row (a=32) = 1.0, both buffers
  if (tid < 16)
    at_lds[(tid >> 3) * (AROWS * ATS) + A_ * ATS + (tid & 7)] = 1.0f;
  // a_t(0) into buffer 0: 8 b x 32 a
  if (tid < 256) {
    const int b = tid >> 5, a = tid & 31;
    at_lds[a * ATS + b] = action[((size_t)(b0 + b) * S_) * A_ + a];
  }

  const int wv = tid >> 6;
  const int mq = tid & 63;
  const int nG = n0 + wv;
  const float* wrow = wa_lds + wv * (LROWS * N_);
  const size_t bump_base = (size_t)B_ * S_ * N_;

  // ---- pin Wa rows 17..31 for (nG, mq) in 60 VGPRs (loaded ONCE) ----
  float4 sw0,sw1,sw2,sw3,sw4,sw5,sw6,sw7,sw8,sw9,sw10,sw11,sw12,sw13,sw14;
  {
    const float* wg = Wa + ((size_t)17 * N_ + nG) * N_ + mq * 4;
    LOADX4(sw0,  wg);           LOADX4(sw1,  wg + 1*NN);
    LOADX4(sw2,  wg + 2*NN);    LOADX4(sw3,  wg + 3*NN);
    LOADX4(sw4,  wg + 4*NN);    LOADX4(sw5,  wg + 5*NN);
    LOADX4(sw6,  wg + 6*NN);    LOADX4(sw7,  wg + 7*NN);
    LOADX4(sw8,  wg + 8*NN);    LOADX4(sw9,  wg + 9*NN);
    LOADX4(sw10, wg + 10*NN);   LOADX4(sw11, wg + 11*NN);
    LOADX4(sw12, wg + 12*NN);   LOADX4(sw13, wg + 13*NN);
    LOADX4(sw14, wg + 14*NN);
  }

  // ---- r0 in registers ----
  float g[4]; float ss = 0.0f;
#pragma unroll
  for (int j = 0; j < 4; ++j) { g[j] = bumpval((float)(mq * 4 + j)); ss += g[j] * g[j]; }
#pragma unroll
  for (int off = 1; off < 64; off <<= 1) ss += __shfl_xor(ss, off, 64);
  const float inv_norm = 1.0f / sqrtf(ss);

  float rr[8][4];
#pragma unroll
  for (int b = 0; b < 8; ++b)
#pragma unroll
    for (int j = 0; j < 4; ++j) rr[b][j] = g[j] * inv_norm;
  float rprev = (mq < 8) ? bumpval((float)nG) * inv_norm : 0.0f;

  __syncthreads();   // LDS ready
  WAIT_VM0();        // sw pinned

  // ---- main scan ----
  for (int t = 0; t < S_; ++t) {
    const float* atb = at_lds + (t & 1) * (AROWS * ATS);

    if (t > 0) {   // r(t): ONE coherent 16B load per thread -> LDS -> regs
      const float* rsrc = rbase + ((t - 1) & 1) * RPAR;
      float4 rq;
      LOADX4_COH(rq, rsrc + tid * 4);
      WAIT_VM0();
      __builtin_amdgcn_sched_barrier(0);
      *reinterpret_cast<float4*>(r_lds + tid * 4) = rq;
      __syncthreads();
#pragma unroll
      for (int b = 0; b < 8; ++b) {
        const float4 rb = *reinterpret_cast<const float4*>(r_lds + b * N_ + mq * 4);
        rr[b][0] = rb.x; rr[b][1] = rb.y; rr[b][2] = rb.z; rr[b][3] = rb.w;
      }
    }

    float acc[8];
#pragma unroll
    for (int b = 0; b < 8; ++b) acc[b] = 0.0f;

#pragma unroll
    for (int a = 0; a < LROWS; ++a) {       // LDS rows; idx 17 = static (at=1)
      const float4 w = *reinterpret_cast<const float4*>(wrow + a * N_ + mq * 4);
      ROWFMA(w, (a < 17) ? a : 32);
    }
    // register-pinned rows a = 17..31
    ROWFMA(sw0, 17);  ROWFMA(sw1, 18);  ROWFMA(sw2, 19);  ROWFMA(sw3, 20);
    ROWFMA(sw4, 21);  ROWFMA(sw5, 22);  ROWFMA(sw6, 23);  ROWFMA(sw7, 24);
    ROWFMA(sw8, 25);  ROWFMA(sw9, 26);  ROWFMA(sw10, 27); ROWFMA(sw11, 28);
    ROWFMA(sw12, 29); ROWFMA(sw13, 30); ROWFMA(sw14, 31);

    // ---- split butterfly: lane mq ends with total for b = mq&7 ----
    const int bit0 = mq & 1, bit1 = mq & 2, bit2 = mq & 4;
    float t0 = bit0 ? acc[1] : acc[0], s0 = bit0 ? acc[0] : acc[1];
    float t1 = bit0 ? acc[3] : acc[2], s1 = bit0 ? acc[2] : acc[3];
    float t2 = bit0 ? acc[5] : acc[4], s2 = bit0 ? acc[4] : acc[5];
    float t3 = bit0 ? acc[7] : acc[6], s3 = bit0 ? acc[6] : acc[7];
    const float u0 = t0 + __shfl_xor(s0, 1, 64);
    const float u1 = t1 + __shfl_xor(s1, 1, 64);
    const float u2 = t2 + __shfl_xor(s2, 1, 64);
    const float u3 = t3 + __shfl_xor(s3, 1, 64);
    const float p0 = bit1 ? u1 : u0, q0 = bit1 ? u0 : u1;
    const float p1 = bit1 ? u3 : u2, q1 = bit1 ? u2 : u3;
    const float m0 = p0 + __shfl_xor(q0, 2, 64);
    const float m1 = p1 + __shfl_xor(q1, 2, 64);
    const float f0 = bit2 ? m1 : m0, g0 = bit2 ? m0 : m1;
    float f = f0 + __shfl_xor(g0, 4, 64);
    f += __shfl_xor(f, 8, 64);
    f += __shfl_xor(f, 16, 64);
    f += __shfl_xor(f, 32, 64);

    float rnew = 0.0f;
    if (mq < 8) {
      rnew = (1.0f - ALPHA_) * rprev + ALPHA_ * fmaxf(f, 0.0f);
      rprev = rnew;
      // [b][n] layout: r[b=mq][nG]
      __hip_atomic_store(rbase + (t & 1) * RPAR + mq * N_ + nG, rnew,
                         __ATOMIC_RELAXED, __HIP_MEMORY_SCOPE_AGENT);
    }

    if (t == S_ - 1) {
      if (mq < 8)
        out[bump_base + ((size_t)(b0 + mq) * S_ + t) * N_ + nG] = rnew;
      break;
    }

    WAIT_VM0();           // r stores acked at LLC (per wave)
    __syncthreads();      // all waves drained
    if (tid == 0)
      __hip_atomic_store(&flags[rank], (unsigned)(t + 1),
                         __ATOMIC_RELAXED, __HIP_MEMORY_SCOPE_AGENT);

    // bump store + next a_t staging overlap the barrier window
    if (mq < 8)
      out[bump_base + ((size_t)(b0 + mq) * S_ + t) * N_ + nG] = rnew;
    if (tid < 256) {
      const int b = tid >> 5, a = tid & 31;
      at_lds[((t + 1) & 1) * (AROWS * ATS) + a * ATS + b] =
          action[((size_t)(b0 + b) * S_ + (t + 1)) * A_ + a];
    }

    if (wv == 0) {        // wave 0 polls the 32 group flags (lanes 0-31 live)
      const unsigned tgt = (unsigned)(t + 1);
      while (true) {
        const unsigned fl = __hip_atomic_load(&flags[mq & 31], __ATOMIC_RELAXED,
                                              __HIP_MEMORY_SCOPE_AGENT);
        if (__all((int)(fl >= tgt))) break;
        __builtin_amdgcn_s_sleep(1);
      }
    }
    __syncthreads();
  }

  // ---- final barrier with device fences (bump visibility for epilogue) ----
  __threadfence();
  __syncthreads();
  if (tid == 0)
    __hip_atomic_store(&flags[rank], 256u, __ATOMIC_RELAXED,
                       __HIP_MEMORY_SCOPE_AGENT);
  if (wv == 0) {
    while (true) {
      const unsigned fl = __hip_atomic_load(&flags[mq & 31], __ATOMIC_RELAXED,
                                            __HIP_MEMORY_SCOPE_AGENT);
      if (__all((int)(fl >= 256u))) break;
      __builtin_amdgcn_s_sleep(1);
    }
  }
  __syncthreads();
  __threadfence();

  // ---- epilogue: rank-2 Wd, this group's rows only ----
  float cm[4], sm[4];
#pragma unroll
  for (int j = 0; j < 4; ++j) {
    const float ang = (float)(mq * 4 + j) * (TWO_PI / N_);
    cm[j] = cosf(ang);
    sm[j] = sinf(ang);
  }
  const float* bump = out + bump_base;
  for (int it = 0; it < 8; ++it) {
    const int row_local = rank * 64 + it * 8 + wv;      // 0..2047 per group
    const int b = b0 + (row_local >> 8);
    const int s = row_local & 255;
    const size_t row = (size_t)b * S_ + s;
    const float4 v = *reinterpret_cast<const float4*>(bump + row * N_ + mq * 4);
    float C  = cm[0]*v.x + cm[1]*v.y + cm[2]*v.z + cm[3]*v.w;
    float Sv = sm[0]*v.x + sm[1]*v.y + sm[2]*v.z + sm[3]*v.w;
#pragma unroll
    for (int off = 1; off < 64; off <<= 1) {
      C  += __shfl_xor(C,  off, 64);
      Sv += __shfl_xor(Sv, off, 64);
    }
    float y[4];
#pragma unroll
    for (int j = 0; j < 4; ++j) y[j] = cm[j] * C + sm[j] * Sv;
    float mx = fmaxf(fmaxf(y[0], y[1]), fmaxf(y[2], y[3]));
#pragma unroll
    for (int off = 1; off < 64; off <<= 1) mx = fmaxf(mx, __shfl_xor(mx, off, 64));
    const float inv = 1.0f / mx;
    *reinterpret_cast<float4*>(out + row * N_ + mq * 4) =
        make_float4(y[0] * inv, y[1] * inv, y[2] * inv, y[3] * inv);
  }
}

extern "C" void kernel_launch(void* const* d_in, const int* in_sizes, int n_in,
                              void* d_out, int out_size, void* d_ws, size_t ws_size,
                              hipStream_t stream) {
  const float* action = (const float*)d_in[0];
  const float* Wo     = (const float*)d_in[1];
  const float* Wa     = (const float*)d_in[2];
  float* out = (float*)d_out;
  float* rws = (float*)d_ws;

  // zero the barrier flags each launch (stream-ordered, capture-safe)
  (void)hipMemsetAsync((char*)d_ws + FLAG_OFF * sizeof(float), 0, 1024, stream);

  (void)hipFuncSetAttribute(reinterpret_cast<const void*>(ring_scan_kernel),
                            hipFuncAttributeMaxDynamicSharedMemorySize, LDS_BYTES);

  void* args[] = {(void*)&action, (void*)&Wo, (void*)&Wa, (void*)&out, (void*)&rws};
  (void)hipLaunchCooperativeKernel(reinterpret_cast<const void*>(ring_scan_kernel),
                                   dim3(256), dim3(512), args,
                                   (unsigned int)LDS_BYTES, stream);
}